// Round 4
// baseline (257.680 us; speedup 1.0000x reference)
//
#include <hip/hip_runtime.h>

// Guided filter r=1, eps=0.01, (8,3,1024,1024) fp32.
// Register-streaming + LDS-DMA staging: vertical-sums-first, 4 cols/lane,
// 2-register sliding vertical windows, single dependent DPP stage per box
// pass. Wave strip: 256 cols x 16 rows. box()/Nrm == sum/count; count applied
// as exact 0.5 / (1/3) row x col factors.
//
// R1: __shfl -> DPP wave shifts (neutral; cross-lane latency not the wall).
// R2 FAILED: depth-2 reg prefetch + sched_barrier + (256,5) -> spills, 700us.
// R3: depth-2 reg prefetch, clean build (VGPR 76, no spills) -> EXACTLY the
//     same 104 us as depth-1. Conclusion: either loads aren't the stall, or
//     the compiler sinks source-level prefetch to its consume point (m131-
//     m141 behavior), making depth irrelevant.
// R4: take schedule ownership: stage rows via __builtin_amdgcn_global_load_lds
//     (async DMA, no VGPR round-trip) into a per-wave 3-slot LDS ring;
//     hand-placed counted `s_waitcnt vmcnt(8)` (never 0) before each consume
//     (T3/T4 pattern). DMA count made wave-uniform (4 events/step: x-row,
//     y-row, x-halo, y-halo; halo from clamped addrs every step, masked at
//     consume; rows clamped at image edges, masked at consume) so the static
//     count is exact. Ring-slot WAR safe: a slot's values are consumed
//     (lgkmcnt-waited) before the overwriting DMA issues one step later.
//     LDS 25.3 KB/block -> 6 blocks/CU (matches VGPR limit).

#define H 1024
#define W 1024
#define STRIP 16      // output rows per wave
#define WAVES 4       // waves per block (stacked vertically)
#define WVC 256       // columns per wave (4 per lane)

typedef const void __attribute__((address_space(1)))* gas1_t;
typedef void __attribute__((address_space(3)))* las3_t;

// lane i receives lane i-1's value (== __shfl_up(v,1,64)); lane 0 -> 0
__device__ __forceinline__ float dpp_up1(float v) {
    return __int_as_float(__builtin_amdgcn_update_dpp(
        0, __float_as_int(v), 0x138 /*wave_shr:1*/, 0xf, 0xf, true));
}
// lane i receives lane i+1's value (== __shfl_down(v,1,64)); lane 63 -> 0
__device__ __forceinline__ float dpp_dn1(float v) {
    return __int_as_float(__builtin_amdgcn_update_dpp(
        0, __float_as_int(v), 0x130 /*wave_shl:1*/, 0xf, 0xf, true));
}

__global__ __launch_bounds__(256, 3) void gf_kernel(const float* __restrict__ xg,
                                                    const float* __restrict__ yg,
                                                    float* __restrict__ og)
{
    // [wave][ring slot][x=0/y=1][own 256 | halo 4 | pad 4]
    __shared__ float lds[WAVES][3][2][264];

    const int lane = threadIdx.x & 63;
    const int wv = threadIdx.x >> 6;
    const int c0 = blockIdx.x * WVC;
    const int R0 = (blockIdx.y * WAVES + wv) * STRIP;
    const size_t base = (size_t)blockIdx.z * (size_t)(H * W);
    const float* __restrict__ xp = xg + base;
    const float* __restrict__ yp = yg + base;
    float* __restrict__ op = og + base;

    const int colA = c0 + 4 * lane;          // first of this lane's 4 columns
    const bool isL = (lane == 0);
    const bool isR = (lane == 63);
    const bool haloIn = isL ? (c0 > 0) : (isR ? (c0 + WVC < W) : false);

    // halo staging column for lanes 0..3 (clamped; garbage masked at consume):
    // lane0 -> c0-2, lane1 -> c0-1, lane2 -> c0+256, lane3 -> c0+257
    int hc = (lane < 2) ? (c0 - 2 + lane) : (c0 + WVC + (lane - 2));
    hc = hc < 0 ? 0 : (hc > W - 1 ? W - 1 : hc);

    const float third = 1.0f / 3.0f;
    float invc[4];
    invc[0] = (colA == 0) ? 0.5f : third;
    invc[1] = third;
    invc[2] = third;
    invc[3] = (colA + 3 == W - 1) ? 0.5f : third;
    const float invcH = haloIn ? third : 0.0f;

    // sliding vertical state: v(new) = p + new; p' = r + new; r' = new
    float pX[4] = {0,0,0,0}, rX[4] = {0,0,0,0};
    float pY[4] = {0,0,0,0}, rY[4] = {0,0,0,0};
    float pXX[4] = {0,0,0,0}, rXX[4] = {0,0,0,0};
    float pXY[4] = {0,0,0,0}, rXY[4] = {0,0,0,0};
    float pHX[2] = {0,0}, rHX[2] = {0,0};
    float pHY[2] = {0,0}, rHY[2] = {0,0};
    float pHXX[2] = {0,0}, rHXX[2] = {0,0};
    float pHXY[2] = {0,0}, rHXY[2] = {0,0};
    float pA[4] = {0,0,0,0}, rA[4] = {0,0,0,0};
    float pB[4] = {0,0,0,0}, rB[4] = {0,0,0,0};
    float pAH = 0, rAH = 0, pBH = 0, rBH = 0;

    // async-stage one row (clamped) into ring slot: exactly 4 vmcnt events.
    auto stage = [&](int row, int slot) {
        const int rb = row * W;
        __builtin_amdgcn_global_load_lds((gas1_t)(xp + rb + colA),
                                         (las3_t)&lds[wv][slot][0][0], 16, 0, 0);
        __builtin_amdgcn_global_load_lds((gas1_t)(yp + rb + colA),
                                         (las3_t)&lds[wv][slot][1][0], 16, 0, 0);
        if (lane < 4) {
            __builtin_amdgcn_global_load_lds((gas1_t)(xp + rb + hc),
                                             (las3_t)&lds[wv][slot][0][256], 4, 0, 0);
            __builtin_amdgcn_global_load_lds((gas1_t)(yp + rb + hc),
                                             (las3_t)&lds[wv][slot][1][256], 4, 0, 0);
        }
    };

    // prologue: rows R0-2 -> slot 0, R0-1 -> slot 1 (clamped low; masked later)
    {
        int r0 = R0 - 2; r0 = r0 < 0 ? 0 : r0;
        int r1 = R0 - 1; r1 = r1 < 0 ? 0 : r1;
        stage(r0, 0);
        stage(r1, 1);
    }

    int slotC = 0;                       // consume slot (s % 3)
    int slotS = 2;                       // stage slot ((s+2) % 3)
    int offSt = (R0 - 4) * W + colA;     // store address tracker

#pragma unroll 2
    for (int s = 0; s < STRIP + 4; ++s) {
        const int lr = R0 - 2 + s;   // row consumed this step
        const int t = lr - 1;        // A,b row produced this step
        const int r = lr - 2;        // output row produced this step

        // ---- issue DMA for row R0+s (always 4 events; row clamped)
        {
            int rs = R0 + s; rs = rs < H ? rs : H - 1;
            stage(rs, slotS);
        }

        // ---- counted wait: leave the two newer steps' 8 loads in flight;
        //      in-order vmcnt retirement => slotC's 4 DMAs are complete.
        asm volatile("s_waitcnt vmcnt(8)" ::: "memory");

        // ---- consume row from LDS (ds_read_b128 x2 + ds_read_b64 x2)
        const bool rowv = ((unsigned)lr < (unsigned)H);
        const float4 xv4 = *(const float4*)&lds[wv][slotC][0][4 * lane];
        const float4 yv4 = *(const float4*)&lds[wv][slotC][1][4 * lane];
        const int hsel = isR ? 258 : 256;
        const float2 xh2 = *(const float2*)&lds[wv][slotC][0][hsel];
        const float2 yh2 = *(const float2*)&lds[wv][slotC][1][hsel];

        const float x_[4] = { rowv ? xv4.x : 0.0f, rowv ? xv4.y : 0.0f,
                              rowv ? xv4.z : 0.0f, rowv ? xv4.w : 0.0f };
        const float y_[4] = { rowv ? yv4.x : 0.0f, rowv ? yv4.y : 0.0f,
                              rowv ? yv4.z : 0.0f, rowv ? yv4.w : 0.0f };
        const bool hv = haloIn && rowv;
        const float xh_[2] = { hv ? xh2.x : 0.0f, hv ? xh2.y : 0.0f };
        const float yh_[2] = { hv ? yh2.x : 0.0f, hv ? yh2.y : 0.0f };

        // ---- products + vertical window update (own 4 cols)
        float vX[4], vY[4], vXX[4], vXY[4];
#pragma unroll
        for (int c = 0; c < 4; ++c) {
            const float xx = x_[c] * x_[c];
            const float xy = x_[c] * y_[c];
            vX[c]  = pX[c]  + x_[c]; pX[c]  = rX[c]  + x_[c]; rX[c]  = x_[c];
            vY[c]  = pY[c]  + y_[c]; pY[c]  = rY[c]  + y_[c]; rY[c]  = y_[c];
            vXX[c] = pXX[c] + xx;    pXX[c] = rXX[c] + xx;    rXX[c] = xx;
            vXY[c] = pXY[c] + xy;    pXY[c] = rXY[c] + xy;    rXY[c] = xy;
        }
        // halo cols (meaningful only on edge lanes; zeros elsewhere)
        float vHX[2], vHY[2], vHXX[2], vHXY[2];
#pragma unroll
        for (int c = 0; c < 2; ++c) {
            const float xx = xh_[c] * xh_[c];
            const float xy = xh_[c] * yh_[c];
            vHX[c]  = pHX[c]  + xh_[c]; pHX[c]  = rHX[c]  + xh_[c]; rHX[c]  = xh_[c];
            vHY[c]  = pHY[c]  + yh_[c]; pHY[c]  = rHY[c]  + yh_[c]; rHY[c]  = yh_[c];
            vHXX[c] = pHXX[c] + xx;     pHXX[c] = rHXX[c] + xx;     rHXX[c] = xx;
            vHXY[c] = pHXY[c] + xy;     pHXY[c] = rHXY[c] + xy;     rHXY[c] = xy;
        }

        // ---- single cross-lane stage on vertical sums (DPP wave shifts)
        float lX  = dpp_up1(vX[3]),  rXs  = dpp_dn1(vX[0]);
        float lY  = dpp_up1(vY[3]),  rYs  = dpp_dn1(vY[0]);
        float lXX = dpp_up1(vXX[3]), rXXs = dpp_dn1(vXX[0]);
        float lXY = dpp_up1(vXY[3]), rXYs = dpp_dn1(vXY[0]);
        lX  = isL ? vHX[1]  : lX;   rXs  = isR ? vHX[0]  : rXs;
        lY  = isL ? vHY[1]  : lY;   rYs  = isR ? vHY[0]  : rYs;
        lXX = isL ? vHXX[1] : lXX;  rXXs = isR ? vHXX[0] : rXXs;
        lXY = isL ? vHXY[1] : lXY;  rXYs = isR ? vHXY[0] : rXYs;

        // ---- horizontal 3-sums (pair-sum trick)
        float hX[4], hY[4], hXX[4], hXY[4];
        {
            const float s01 = vX[0] + vX[1], s12 = vX[1] + vX[2], s23 = vX[2] + vX[3];
            hX[0] = lX + s01; hX[1] = s01 + vX[2]; hX[2] = s12 + vX[3]; hX[3] = s23 + rXs;
        }
        {
            const float s01 = vY[0] + vY[1], s12 = vY[1] + vY[2], s23 = vY[2] + vY[3];
            hY[0] = lY + s01; hY[1] = s01 + vY[2]; hY[2] = s12 + vY[3]; hY[3] = s23 + rYs;
        }
        {
            const float s01 = vXX[0] + vXX[1], s12 = vXX[1] + vXX[2], s23 = vXX[2] + vXX[3];
            hXX[0] = lXX + s01; hXX[1] = s01 + vXX[2]; hXX[2] = s12 + vXX[3]; hXX[3] = s23 + rXXs;
        }
        {
            const float s01 = vXY[0] + vXY[1], s12 = vXY[1] + vXY[2], s23 = vXY[2] + vXY[3];
            hXY[0] = lXY + s01; hXY[1] = s01 + vXY[2]; hXY[2] = s12 + vXY[3]; hXY[3] = s23 + rXYs;
        }

        // ---- stage 1: A,b for row t (rowfA=0 outside image zeroes everything)
        const float rowfA = ((unsigned)t >= (unsigned)H) ? 0.0f
                          : ((t == 0 || t == H - 1) ? 0.5f : third);
        float A_[4], B_[4];
#pragma unroll
        for (int c = 0; c < 4; ++c) {
            const float ic  = rowfA * invc[c];
            const float mx  = hX[c]  * ic;
            const float my  = hY[c]  * ic;
            const float mxx = hXX[c] * ic;
            const float mxy = hXY[c] * ic;
            const float var = fmaf(-mx, mx, mxx);
            const float cov = fmaf(-mx, my, mxy);
            A_[c] = cov * __builtin_amdgcn_rcpf(var + 0.01f);
            B_[c] = fmaf(-A_[c], mx, my);
        }
        // halo-column A,b (one per edge lane; garbage-but-finite elsewhere)
        float AH, BH;
        {
            const float iH  = rowfA * invcH;
            const float hx  = vHX[0]  + vHX[1]  + (isL ? vX[0]  : vX[3]);
            const float hy  = vHY[0]  + vHY[1]  + (isL ? vY[0]  : vY[3]);
            const float hxx = vHXX[0] + vHXX[1] + (isL ? vXX[0] : vXX[3]);
            const float hxy = vHXY[0] + vHXY[1] + (isL ? vXY[0] : vXY[3]);
            const float mx  = hx * iH, my = hy * iH, mxx = hxx * iH, mxy = hxy * iH;
            const float var = fmaf(-mx, mx, mxx);
            const float cov = fmaf(-mx, my, mxy);
            AH = cov * __builtin_amdgcn_rcpf(var + 0.01f);
            BH = fmaf(-AH, mx, my);
        }

        // ---- A,b vertical windows
        float vA[4], vB[4];
#pragma unroll
        for (int c = 0; c < 4; ++c) {
            vA[c] = pA[c] + A_[c]; pA[c] = rA[c] + A_[c]; rA[c] = A_[c];
            vB[c] = pB[c] + B_[c]; pB[c] = rB[c] + B_[c]; rB[c] = B_[c];
        }
        const float vAH = pAH + AH;  pAH = rAH + AH;  rAH = AH;
        const float vBH = pBH + BH;  pBH = rBH + BH;  rBH = BH;

        // ---- cross-lane stage on A,b vertical sums (DPP wave shifts)
        float lA = dpp_up1(vA[3]), rAs = dpp_dn1(vA[0]);
        float lB = dpp_up1(vB[3]), rBs = dpp_dn1(vB[0]);
        lA = isL ? vAH : lA;  rAs = isR ? vAH : rAs;
        lB = isL ? vBH : lB;  rBs = isR ? vBH : rBs;

        // ---- output row r
        if (s >= 4) {
            float hA[4], hB[4];
            {
                const float s01 = vA[0] + vA[1], s12 = vA[1] + vA[2], s23 = vA[2] + vA[3];
                hA[0] = lA + s01; hA[1] = s01 + vA[2]; hA[2] = s12 + vA[3]; hA[3] = s23 + rAs;
            }
            {
                const float s01 = vB[0] + vB[1], s12 = vB[1] + vB[2], s23 = vB[2] + vB[3];
                hB[0] = lB + s01; hB[1] = s01 + vB[2]; hB[2] = s12 + vB[3]; hB[3] = s23 + rBs;
            }
            const float rowfO = (r == 0 || r == H - 1) ? 0.5f : third;
            float4 o;
            float o_[4];
#pragma unroll
            for (int c = 0; c < 4; ++c) {
                const float oc = rowfO * invc[c];
                const float xc = vX[c] - pX[c];     // = x at row r (post-update identity)
                o_[c] = fmaf(hA[c] * oc, xc, hB[c] * oc);
            }
            o.x = o_[0]; o.y = o_[1]; o.z = o_[2]; o.w = o_[3];
            *(float4*)(op + offSt) = o;
        }

        // ---- rotate ring slots, advance store row
        slotC = (slotC == 2) ? 0 : slotC + 1;
        slotS = (slotS == 2) ? 0 : slotS + 1;
        offSt += W;
    }
}

extern "C" void kernel_launch(void* const* d_in, const int* in_sizes, int n_in,
                              void* d_out, int out_size, void* d_ws, size_t ws_size,
                              hipStream_t stream) {
    const float* x = (const float*)d_in[0];
    const float* y = (const float*)d_in[1];
    float* out = (float*)d_out;
    const int planes = in_sizes[0] / (H * W);                  // N*C = 24
    dim3 grid(W / WVC, H / (STRIP * WAVES), planes);           // 4 x 16 x 24 = 1536
    gf_kernel<<<grid, dim3(256), 0, stream>>>(x, y, out);
}

// Round 6
// 253.099 us; speedup vs baseline: 1.0181x; 1.0181x over previous
//
#include <hip/hip_runtime.h>

// Guided filter r=1, eps=0.01, (8,3,1024,1024) fp32.
// Register-streaming, packed-FP32 edition: vertical-sums-first, 4 cols/lane,
// 2-register sliding vertical windows, single dependent DPP stage per box
// pass. Wave strip: 256 cols x 16 rows. box()/Nrm == sum/count, applied as
// exact 0.5 / (1/3) row x col factors.
//
// R1: __shfl -> DPP wave shifts (neutral).
// R2 FAILED: prefetch + sched_barrier + (256,5) -> spills, 700us.
// R3: depth-2 reg prefetch, clean (76 VGPR) -> identical 104us to depth-1.
// R4: LDS-DMA ring + counted vmcnt(8) -> 110us, VALUBusy unchanged 44%.
//     => input-load latency is NOT the wall (3 structures, same result).
// R5 FAILED (absmax 1.65): packed fp32 was right, but DPP was moved into a
//     ternary's else-arm. update_dpp is convergent -> not speculatable ->
//     executes under divergent exec with lane0/63 masked off; bound_ctrl=1
//     makes reads FROM an inactive lane return 0 -> lanes 1/62 got zeros.
// R6: same packed arithmetic; DPP computed UNCONDITIONALLY in uniform
//     control flow (R1-R4 structure), then patched with pure-data selects.

typedef float v2f __attribute__((ext_vector_type(2)));

#define H 1024
#define W 1024
#define STRIP 16      // output rows per wave
#define WAVES 4       // waves per block (stacked vertically)
#define WVC 256       // columns per wave (4 per lane)

// lane i receives lane i-1's value (== __shfl_up(v,1,64)); lane 0 -> 0
__device__ __forceinline__ float dpp_up1(float v) {
    return __int_as_float(__builtin_amdgcn_update_dpp(
        0, __float_as_int(v), 0x138 /*wave_shr:1*/, 0xf, 0xf, true));
}
// lane i receives lane i+1's value (== __shfl_down(v,1,64)); lane 63 -> 0
__device__ __forceinline__ float dpp_dn1(float v) {
    return __int_as_float(__builtin_amdgcn_update_dpp(
        0, __float_as_int(v), 0x130 /*wave_shl:1*/, 0xf, 0xf, true));
}
__device__ __forceinline__ v2f dpp_up2(v2f v) {
    v2f o; o.x = dpp_up1(v.x); o.y = dpp_up1(v.y); return o;
}
__device__ __forceinline__ v2f dpp_dn2(v2f v) {
    v2f o; o.x = dpp_dn1(v.x); o.y = dpp_dn1(v.y); return o;
}

__global__ __launch_bounds__(256, 3) void gf_kernel(const float* __restrict__ xg,
                                                    const float* __restrict__ yg,
                                                    float* __restrict__ og)
{
    const int lane = threadIdx.x & 63;
    const int wv = threadIdx.x >> 6;
    const int c0 = blockIdx.x * WVC;
    const int R0 = (blockIdx.y * WAVES + wv) * STRIP;
    const size_t base = (size_t)blockIdx.z * (size_t)(H * W);
    const float* __restrict__ xp = xg + base;
    const float* __restrict__ yp = yg + base;
    float* __restrict__ op = og + base;

    const int colA = c0 + 4 * lane;          // first of this lane's 4 columns
    const bool isL = (lane == 0);
    const bool isR = (lane == 63);
    // lane0 halo cols: c0-2 (h0), c0-1 (h1).  lane63: c0+256 (h0), c0+257 (h1).
    const bool haloIn = isL ? (c0 > 0) : (isR ? (c0 + WVC < W) : false);
    const int hoff = (isL ? (c0 - 2) : (c0 + WVC)) - colA;

    const float third = 1.0f / 3.0f;
    float invc[4];
    invc[0] = (colA == 0) ? 0.5f : third;
    invc[1] = third;
    invc[2] = third;
    invc[3] = (colA + 3 == W - 1) ? 0.5f : third;
    const float invcH = haloIn ? third : 0.0f;

    // sliding vertical state (packed): S=(x,y), Q=(xx,xy), AB=(A,b)
    // v(new) = p + new; p' = r + new; r' = new
    v2f pS[4] = {}, rS[4] = {};
    v2f pQ[4] = {}, rQ[4] = {};
    v2f pHS[2] = {}, rHS[2] = {};
    v2f pHQ[2] = {}, rHQ[2] = {};
    v2f pAB[4] = {}, rAB[4] = {};
    v2f pABH = {0.0f, 0.0f}, rABH = {0.0f, 0.0f};

    int off = (R0 - 2) * W + colA;

    // prime the 2-deep pipeline: row R0-2 -> xv (consumed s=0),
    //                            row R0-1 -> xv1 (consumed s=1)
    float4 xv  = {0,0,0,0}, yv  = {0,0,0,0};
    float2 xh  = {0,0},     yh  = {0,0};
    float4 xv1 = {0,0,0,0}, yv1 = {0,0,0,0};
    float2 xh1 = {0,0},     yh1 = {0,0};
    if (R0 - 2 >= 0) {
        xv = *(const float4*)(xp + off);
        yv = *(const float4*)(yp + off);
        if (haloIn) {
            xh = *(const float2*)(xp + off + hoff);
            yh = *(const float2*)(yp + off + hoff);
        }
    }
    if (R0 - 1 >= 0) {
        xv1 = *(const float4*)(xp + off + W);
        yv1 = *(const float4*)(yp + off + W);
        if (haloIn) {
            xh1 = *(const float2*)(xp + off + W + hoff);
            yh1 = *(const float2*)(yp + off + W + hoff);
        }
    }

#pragma unroll 2
    for (int s = 0; s < STRIP + 4; ++s) {
        const int lr = R0 - 2 + s;   // row held in xv/yv (consumed this step)
        const int t = lr - 1;        // A,b row produced this step
        const int r = lr - 2;        // output row produced this step

        // ---- issue loads for row lr+2 == R0+s (depth-2 prefetch)
        float4 xv2 = {0,0,0,0}, yv2 = {0,0,0,0};
        float2 xh2 = {0,0}, yh2 = {0,0};
        if (s < STRIP + 2 && (unsigned)(R0 + s) < (unsigned)H) {
            const int off2 = off + 2 * W;
            xv2 = *(const float4*)(xp + off2);
            yv2 = *(const float4*)(yp + off2);
            if (haloIn) {
                xh2 = *(const float2*)(xp + off2 + hoff);
                yh2 = *(const float2*)(yp + off2 + hoff);
            }
        }

        // ---- products + vertical window update (own 4 cols, packed)
        const float x_[4] = {xv.x, xv.y, xv.z, xv.w};
        const float y_[4] = {yv.x, yv.y, yv.z, yv.w};
        v2f vS[4], vQ[4];
#pragma unroll
        for (int c = 0; c < 4; ++c) {
            v2f sv; sv.x = x_[c]; sv.y = y_[c];          // (x, y)
            v2f xs; xs.x = x_[c]; xs.y = x_[c];
            const v2f q = sv * xs;                       // (xx, xy)
            vS[c] = pS[c] + sv; pS[c] = rS[c] + sv; rS[c] = sv;
            vQ[c] = pQ[c] + q;  pQ[c] = rQ[c] + q;  rQ[c] = q;
        }
        // halo cols (meaningful only on edge lanes; zeros elsewhere)
        const float xh_[2] = {xh.x, xh.y};
        const float yh_[2] = {yh.x, yh.y};
        v2f vHS[2], vHQ[2];
#pragma unroll
        for (int c = 0; c < 2; ++c) {
            v2f sv; sv.x = xh_[c]; sv.y = yh_[c];
            v2f xs; xs.x = xh_[c]; xs.y = xh_[c];
            const v2f q = sv * xs;
            vHS[c] = pHS[c] + sv; pHS[c] = rHS[c] + sv; rHS[c] = sv;
            vHQ[c] = pHQ[c] + q;  pHQ[c] = rHQ[c] + q;  rHQ[c] = q;
        }

        // ---- cross-lane stage on vertical sums: DPP computed UNCONDITIONALLY
        //      (uniform exec; convergent op must not sit under a divergent
        //      branch), then patched with pure-data selects.
        v2f lS  = dpp_up2(vS[3]);
        v2f rSs = dpp_dn2(vS[0]);
        v2f lQ  = dpp_up2(vQ[3]);
        v2f rQs = dpp_dn2(vQ[0]);
        lS  = isL ? vHS[1] : lS;   rSs = isR ? vHS[0] : rSs;
        lQ  = isL ? vHQ[1] : lQ;   rQs = isR ? vHQ[0] : rQs;

        // ---- horizontal 3-sums (pair-sum trick, packed)
        v2f hS[4], hQ[4];
        {
            const v2f s01 = vS[0] + vS[1], s12 = vS[1] + vS[2], s23 = vS[2] + vS[3];
            hS[0] = lS + s01; hS[1] = s01 + vS[2]; hS[2] = s12 + vS[3]; hS[3] = s23 + rSs;
        }
        {
            const v2f s01 = vQ[0] + vQ[1], s12 = vQ[1] + vQ[2], s23 = vQ[2] + vQ[3];
            hQ[0] = lQ + s01; hQ[1] = s01 + vQ[2]; hQ[2] = s12 + vQ[3]; hQ[3] = s23 + rQs;
        }

        // ---- stage 1: A,b for row t (rowfA=0 outside image zeroes everything)
        const float rowfA = ((unsigned)t >= (unsigned)H) ? 0.0f
                          : ((t == 0 || t == H - 1) ? 0.5f : third);
        float A_[4], B_[4];
#pragma unroll
        for (int c = 0; c < 4; ++c) {
            const float ic = rowfA * invc[c];
            v2f ic2; ic2.x = ic; ic2.y = ic;
            const v2f m  = hS[c] * ic2;                  // (mx, my)
            const v2f qq = hQ[c] * ic2;                  // (mxx, mxy)
            v2f nm; nm.x = -m.x; nm.y = -m.x;
            const v2f vc = nm * m + qq;                  // (var, cov) via pk_fma
            const float Ac = vc.y * __builtin_amdgcn_rcpf(vc.x + 0.01f);
            A_[c] = Ac;
            B_[c] = fmaf(-Ac, m.x, m.y);
        }
        // halo-column A,b (one per edge lane; garbage-but-finite elsewhere)
        float AH, BH;
        {
            const float iH = rowfA * invcH;
            v2f iH2; iH2.x = iH; iH2.y = iH;
            const v2f hSh = vHS[0] + vHS[1] + (isL ? vS[0] : vS[3]);
            const v2f hQh = vHQ[0] + vHQ[1] + (isL ? vQ[0] : vQ[3]);
            const v2f m  = hSh * iH2;
            const v2f qq = hQh * iH2;
            v2f nm; nm.x = -m.x; nm.y = -m.x;
            const v2f vc = nm * m + qq;
            AH = vc.y * __builtin_amdgcn_rcpf(vc.x + 0.01f);
            BH = fmaf(-AH, m.x, m.y);
        }

        // ---- A,b vertical windows (packed)
        v2f vAB[4];
#pragma unroll
        for (int c = 0; c < 4; ++c) {
            v2f ab; ab.x = A_[c]; ab.y = B_[c];
            vAB[c] = pAB[c] + ab; pAB[c] = rAB[c] + ab; rAB[c] = ab;
        }
        v2f abh; abh.x = AH; abh.y = BH;
        const v2f vABH = pABH + abh;  pABH = rABH + abh;  rABH = abh;

        // ---- cross-lane stage on A,b sums (unconditional DPP, then select)
        v2f lAB  = dpp_up2(vAB[3]);
        v2f rABs = dpp_dn2(vAB[0]);
        lAB  = isL ? vABH : lAB;
        rABs = isR ? vABH : rABs;

        // ---- output row r
        if (s >= 4) {
            v2f hAB[4];
            {
                const v2f s01 = vAB[0] + vAB[1], s12 = vAB[1] + vAB[2], s23 = vAB[2] + vAB[3];
                hAB[0] = lAB + s01; hAB[1] = s01 + vAB[2]; hAB[2] = s12 + vAB[3]; hAB[3] = s23 + rABs;
            }
            const float rowfO = (r == 0 || r == H - 1) ? 0.5f : third;
            float4 o;
            float o_[4];
#pragma unroll
            for (int c = 0; c < 4; ++c) {
                const float oc = rowfO * invc[c];
                v2f oc2; oc2.x = oc; oc2.y = oc;
                const v2f tt = hAB[c] * oc2;             // (A*oc, b*oc)
                const float xc = vS[c].x - pS[c].x;      // = x at row r
                o_[c] = fmaf(tt.x, xc, tt.y);
            }
            o.x = o_[0]; o.y = o_[1]; o.z = o_[2]; o.w = o_[3];
            *(float4*)(op + (off - 2 * W)) = o;
        }

        // rotate the 2-deep pipeline (renamed by unroll-2, mostly no movs)
        xv = xv1;  yv = yv1;  xh = xh1;  yh = yh1;
        xv1 = xv2; yv1 = yv2; xh1 = xh2; yh1 = yh2;
        off += W;
    }
}

extern "C" void kernel_launch(void* const* d_in, const int* in_sizes, int n_in,
                              void* d_out, int out_size, void* d_ws, size_t ws_size,
                              hipStream_t stream) {
    const float* x = (const float*)d_in[0];
    const float* y = (const float*)d_in[1];
    float* out = (float*)d_out;
    const int planes = in_sizes[0] / (H * W);                  // N*C = 24
    dim3 grid(W / WVC, H / (STRIP * WAVES), planes);           // 4 x 16 x 24 = 1536
    gf_kernel<<<grid, dim3(256), 0, stream>>>(x, y, out);
}